// Round 4
// baseline (1642.008 us; speedup 1.0000x reference)
//
#include <hip/hip_runtime.h>
#include <cstddef>

#define NROWS 16384
#define NE    8192
#define DD    256
#define TM    256
#define TN    128
#define BK    32
#define NCH   8
#define CHW   (NE / NCH)   // 1024 cols per chunk

typedef unsigned long long u64;
typedef float vf4 __attribute__((ext_vector_type(4)));

// ---------------------------------------------------------------------------
// k_rowsq: zsq[n] = sum(z[n,:]^2) in numpy pairwise order (256 = 128+128,
// each 128-block via 8 strided accumulators). esq likewise. Also inits
// best[] to u64-max, zeroes counts + loss accumulator.
// ---------------------------------------------------------------------------
__global__ __launch_bounds__(256) void k_rowsq(
    const float* __restrict__ z, const float* __restrict__ emb,
    float* __restrict__ zsq, float* __restrict__ esq,
    u64* __restrict__ best, int* __restrict__ counts,
    float* __restrict__ loss_acc)
{
  const int g = blockIdx.x * 256 + threadIdx.x;   // 0 .. 24575
  if (g < NE) counts[g] = 0;
  if (g < NROWS) best[g] = ~0ull;
  if (g == 0) *loss_acc = 0.0f;

  const float* row;
  float* outp;
  if (g < NROWS) { row = z + (size_t)g * DD;            outp = zsq + g; }
  else           { row = emb + (size_t)(g - NROWS) * DD; outp = esq + (g - NROWS); }

  float half_s[2];
#pragma unroll
  for (int h = 0; h < 2; ++h) {
    const float* p = row + h * 128;
    float r[8];
#pragma unroll
    for (int j = 0; j < 8; ++j) {
      float x = p[j];
      float sq = x * x;
      asm volatile("" : "+v"(sq));   // block FMA contraction: np rounds x*x first
      r[j] = sq;
    }
    for (int i = 8; i < 128; i += 8) {
#pragma unroll
      for (int j = 0; j < 8; ++j) {
        float x = p[i + j];
        float sq = x * x;
        asm volatile("" : "+v"(sq));
        r[j] = r[j] + sq;
      }
    }
    half_s[h] = ((r[0] + r[1]) + (r[2] + r[3])) + ((r[4] + r[5]) + (r[6] + r[7]));
  }
  *outp = half_s[0] + half_s[1];
}

// ---------------------------------------------------------------------------
// k_argmin v3: 256x128 block tile, 256 threads, 16x8 micro-tile.
// Thread rows: ty*4 + {0..3} + 64*{0..3}; cols: tx*4 + {0..3} + 64*{0,1}.
// Per kk: 6 ds_read_b128 per 128 FMAs (0.375 B/FLOP) -> LDS pipe ~89% cap.
// Columns split into 8 chunks (blockIdx.y); cross-block reduce via atomicMin
// on packed (float_bits(d)<<32)|col — d>0, bits order-preserving, lowest
// index wins ties (matches np argmin). Accumulation: sequential k, FMA —
// identical order to rounds 1/3 (bit-exact match confirmed).
// ---------------------------------------------------------------------------
__global__ __launch_bounds__(256, 2) void k_argmin(
    const float* __restrict__ z, const float* __restrict__ emb,
    const float* __restrict__ zsq, const float* __restrict__ esq,
    u64* __restrict__ best)
{
  __shared__ float As[BK][TM];          // 32 KB
  __shared__ float Bs[BK][TN];          // 16 KB

  const int tid = threadIdx.x;
  const int tx = tid & 15;
  const int ty = tid >> 4;
  const int tx4 = tx * 4;
  const int ty4 = ty * 4;
  const int R0 = blockIdx.x * TM;
  const int C0 = blockIdx.y * CHW;

  const int bcol  = tid & 127;          // B staging col
  const int bkoff = (tid >> 7) * 16;    // B staging k-half

  float zr[16];
#pragma unroll
  for (int i = 0; i < 16; ++i)
    zr[i] = zsq[R0 + (i >> 2) * 64 + ty4 + (i & 3)];

  u64 bp[16];
#pragma unroll
  for (int i = 0; i < 16; ++i) bp[i] = ~0ull;

  for (int t = 0; t < CHW; t += TN) {
    const int Cb = C0 + t;
    float acc[16][8];
#pragma unroll
    for (int i = 0; i < 16; ++i)
#pragma unroll
      for (int j = 0; j < 8; ++j) acc[i][j] = 0.0f;

    for (int k0 = 0; k0 < DD; k0 += BK) {
      __syncthreads();
      // A: each thread stages its own row's 32-k slice (row = R0+tid)
#pragma unroll
      for (int q = 0; q < 8; ++q) {
        const float4 v = *(const float4*)(z + (size_t)(R0 + tid) * DD + k0 + 4 * q);
        As[4 * q + 0][tid] = v.x;
        As[4 * q + 1][tid] = v.y;
        As[4 * q + 2][tid] = v.z;
        As[4 * q + 3][tid] = v.w;
      }
      // B: 128 cols x 32 k, two thread-halves take k-halves
#pragma unroll
      for (int q = 0; q < 4; ++q) {
        const float4 v = *(const float4*)(emb + (size_t)(Cb + bcol) * DD + k0 + bkoff + 4 * q);
        Bs[bkoff + 4 * q + 0][bcol] = v.x;
        Bs[bkoff + 4 * q + 1][bcol] = v.y;
        Bs[bkoff + 4 * q + 2][bcol] = v.z;
        Bs[bkoff + 4 * q + 3][bcol] = v.w;
      }
      __syncthreads();
#pragma unroll 8
      for (int kk = 0; kk < BK; ++kk) {
        const float4 a0 = *(const float4*)(&As[kk][ty4]);
        const float4 a1 = *(const float4*)(&As[kk][ty4 + 64]);
        const float4 a2 = *(const float4*)(&As[kk][ty4 + 128]);
        const float4 a3 = *(const float4*)(&As[kk][ty4 + 192]);
        const float4 b0 = *(const float4*)(&Bs[kk][tx4]);
        const float4 b1 = *(const float4*)(&Bs[kk][tx4 + 64]);
        const float av[16] = {a0.x, a0.y, a0.z, a0.w, a1.x, a1.y, a1.z, a1.w,
                              a2.x, a2.y, a2.z, a2.w, a3.x, a3.y, a3.z, a3.w};
        const float bv[8]  = {b0.x, b0.y, b0.z, b0.w, b1.x, b1.y, b1.z, b1.w};
#pragma unroll
        for (int i = 0; i < 16; ++i)
#pragma unroll
          for (int j = 0; j < 8; ++j)
            acc[i][j] += av[i] * bv[j];
      }
    }

#pragma unroll
    for (int j = 0; j < 8; ++j) {
      const int col = Cb + tx4 + ((j < 4) ? j : 64 + j - 4);
      const float ev = esq[col];
#pragma unroll
      for (int i = 0; i < 16; ++i) {
        const float s1 = zr[i] + ev;              // fl(zsq+esq), matches np
        const float dv = s1 - 2.0f * acc[i][j];   // fl(s1 - 2*dot); 2*dot exact
        const u64 p = ((u64)__float_as_uint(dv) << 32) | (unsigned)col;
        if (p < bp[i]) bp[i] = p;
      }
    }
  }

  // reduce across the 16 tx lanes (contiguous 16-lane groups share ty)
#pragma unroll
  for (int i = 0; i < 16; ++i) {
#pragma unroll
    for (int off = 8; off > 0; off >>= 1) {
      const u64 o = __shfl_xor(bp[i], off, 16);
      if (o < bp[i]) bp[i] = o;
    }
  }
  if (tx == 0) {
#pragma unroll
    for (int i = 0; i < 16; ++i) {
      const int r = R0 + (i >> 2) * 64 + ty4 + (i & 3);
      atomicMin(&best[r], bp[i]);
    }
  }
}

// ---------------------------------------------------------------------------
// k_zero: zero the 537 MB one-hot region. Base is only 8B-aligned
// (out + 4194306), so handle a 2-float head/tail and vf4 the aligned middle.
// ---------------------------------------------------------------------------
#define OH_TOT   ((size_t)NROWS * NE)            // 134217728 floats
#define OH_VEC   ((OH_TOT - 4) / 4)              // 33554431 vf4 stores
__global__ __launch_bounds__(256) void k_zero(float* __restrict__ base)
{
  const size_t i0 = (size_t)blockIdx.x * 256 + threadIdx.x;
  const size_t stride = (size_t)gridDim.x * 256;
  vf4 zero = {0.0f, 0.0f, 0.0f, 0.0f};
  float* p = base + 2;                           // 16B-aligned
  for (size_t t = i0; t < OH_VEC; t += stride)
    *(vf4*)(p + 4 * t) = zero;
  if (i0 == 0) {
    base[0] = 0.0f; base[1] = 0.0f;
    base[OH_TOT - 2] = 0.0f; base[OH_TOT - 1] = 0.0f;
  }
}

// ---------------------------------------------------------------------------
// k_scatter: one 64-lane group per row. Gathers z_q, writes the one-hot 1.0,
// float(index), loss partials, counts.
// ---------------------------------------------------------------------------
__global__ __launch_bounds__(256) void k_scatter(
    const float* __restrict__ z, const float* __restrict__ emb,
    const u64* __restrict__ best,
    float* __restrict__ out_zq, float* __restrict__ out_onehot,
    float* __restrict__ out_idx, float* __restrict__ loss_acc,
    int* __restrict__ counts)
{
  const int row = blockIdx.x * 4 + (threadIdx.x >> 6);
  const int lane = threadIdx.x & 63;
  const int idx = (int)(unsigned)(best[row] & 0xffffffffull);
  const int k0 = lane * 4;

  const float4 e  = *(const float4*)(emb + (size_t)idx * DD + k0);
  const float4 zv = *(const float4*)(z + (size_t)row * DD + k0);
  *(float4*)(out_zq + (size_t)row * DD + k0) = e;

  const float dx = e.x - zv.x, dy = e.y - zv.y, dz = e.z - zv.z, dw = e.w - zv.w;
  float local = dx * dx + dy * dy + dz * dz + dw * dw;
#pragma unroll
  for (int off = 32; off > 0; off >>= 1) local += __shfl_down(local, off, 64);
  if (lane == 0) {
    atomicAdd(loss_acc, local);
    out_idx[row] = (float)idx;
    out_onehot[(size_t)row * NE + idx] = 1.0f;
    atomicAdd(&counts[idx], 1);
  }
}

// ---------------------------------------------------------------------------
// k_final: perplexity = exp(-sum(p*log(p+1e-10))), loss = 1.25 * mean.
// ---------------------------------------------------------------------------
__global__ __launch_bounds__(256) void k_final(
    const int* __restrict__ counts, const float* __restrict__ loss_acc,
    float* __restrict__ out_loss, float* __restrict__ out_perp)
{
  __shared__ float sred[256];
  float local = 0.0f;
  for (int e = threadIdx.x; e < NE; e += 256) {
    const float p = (float)counts[e] * (1.0f / 16384.0f);
    local += p * logf(p + 1e-10f);
  }
  sred[threadIdx.x] = local;
  __syncthreads();
  for (int s = 128; s > 0; s >>= 1) {
    if (threadIdx.x < s) sred[threadIdx.x] += sred[threadIdx.x + s];
    __syncthreads();
  }
  if (threadIdx.x == 0) {
    *out_perp = expf(-sred[0]);
    *out_loss = *loss_acc * (1.25f / 4194304.0f);  // (1+beta) * sum / (N*D)
  }
}

// ---------------------------------------------------------------------------
// Output layout (float32, concatenated in reference return order):
//   [0]                loss                       (1)
//   [1 .. 4194304]     z_q_st                     (16384*256)
//   [4194305]          perplexity                 (1)
//   [4194306 ..]       min_encodings one-hot      (16384*8192)
//   [138412034 ..]     min_encoding_indices       (16384, written as float)
// ---------------------------------------------------------------------------
extern "C" void kernel_launch(void* const* d_in, const int* in_sizes, int n_in,
                              void* d_out, int out_size, void* d_ws, size_t ws_size,
                              hipStream_t stream) {
  const float* z   = (const float*)d_in[0];
  const float* emb = (const float*)d_in[1];

  float* out        = (float*)d_out;
  float* out_loss   = out;
  float* out_zq     = out + 1;
  float* out_perp   = out + 4194305;
  float* out_onehot = out + 4194306;
  float* out_idx    = out + 138412034;

  float* zsq      = (float*)d_ws;            // 16384 f
  float* esq      = zsq + NROWS;             // 8192 f
  u64*   best     = (u64*)(esq + NE);        // 16384 u64 (8B-aligned: offset 96 KB)
  int*   counts   = (int*)(best + NROWS);    // 8192 int
  float* loss_acc = (float*)(counts + NE);   // 1 f

  k_zero<<<2048, 256, 0, stream>>>(out_onehot);
  k_rowsq<<<96, 256, 0, stream>>>(z, emb, zsq, esq, best, counts, loss_acc);
  k_argmin<<<dim3(NROWS / TM, NCH), 256, 0, stream>>>(z, emb, zsq, esq, best);
  k_scatter<<<NROWS / 4, 256, 0, stream>>>(z, emb, best, out_zq, out_onehot,
                                           out_idx, loss_acc, counts);
  k_final<<<1, 256, 0, stream>>>(counts, loss_acc, out_loss, out_perp);
}